// Round 7
// baseline (279.329 us; speedup 1.0000x reference)
//
#include <hip/hip_runtime.h>
#include <hip/hip_bf16.h>
#include <cstdint>

// Toy MultiHeadAttention: B=2, L=2048, D=1024, H=16, HD=64, causal, eval (no dropout)
// Pipeline: fp32->bf16 converts; QKV GEMM (bf16 MFMA) with Q/K/Vt scatter epilogue;
// causal flash attention (swapped-QK^T; softmax per-lane; P feeds PV directly as the
// 16x16x16 MFMA B-fragment -- no transpose shuffles, no LDS); out GEMM + bias.

typedef __attribute__((ext_vector_type(8))) short sh8;    // 8 bf16 (4 VGPRs) for 16x16x32
typedef __attribute__((ext_vector_type(4))) short sh4;    // 4 bf16 (2 VGPRs) for 16x16x16
typedef __attribute__((ext_vector_type(4))) float f32x4;  // MFMA C/D frag

__device__ __forceinline__ unsigned short f2b(float f) {  // fp32 -> bf16 RNE
  unsigned int u = __float_as_uint(f);
  u += 0x7FFFu + ((u >> 16) & 1u);
  return (unsigned short)(u >> 16);
}

__device__ __forceinline__ unsigned int pack2(float lo, float hi) {  // 2xbf16 in u32
  return (unsigned int)f2b(lo) | ((unsigned int)f2b(hi) << 16);
}

__device__ __forceinline__ f32x4 mfma16x16x16(sh4 a, sh4 b, f32x4 c) {
#if __has_builtin(__builtin_amdgcn_mfma_f32_16x16x16bf16_1k)
  return __builtin_amdgcn_mfma_f32_16x16x16bf16_1k(a, b, c, 0, 0, 0);
#else
  asm volatile("v_mfma_f32_16x16x16_bf16 %0, %1, %2, %0" : "+v"(c) : "v"(a), "v"(b));
  return c;
#endif
}

__device__ __forceinline__ void gload_lds16(const void* g, void* l) {
  __builtin_amdgcn_global_load_lds((__attribute__((address_space(1))) void*)g,
                                   (__attribute__((address_space(3))) void*)l,
                                   16, 0, 0);
}

// ---------------- fp32 -> bf16 convert (vectorized) ----------------
__global__ __launch_bounds__(256) void k_cvt(const float* __restrict__ in,
                                             unsigned short* __restrict__ out, int n) {
  int idx = (blockIdx.x * 256 + threadIdx.x) * 4;
  if (idx >= n) return;
  float4 v = *(const float4*)&in[idx];
  union { unsigned short u[4]; uint2 w; } r;
  r.u[0] = f2b(v.x); r.u[1] = f2b(v.y); r.u[2] = f2b(v.z); r.u[3] = f2b(v.w);
  *(uint2*)&out[idx] = r.w;
}

// ---------------- shared GEMM core: C[128x128] = A[M,K] * B[N,K]^T ----------------
__device__ __forceinline__ void gemm_bt_core(
    const unsigned short* __restrict__ A,   // [M][K] bf16 row-major
    const unsigned short* __restrict__ B,   // [N][K] bf16 row-major
    int K, int m0, int n0,
    unsigned short* ldsA, unsigned short* ldsB,
    f32x4 acc[4][4]) {
  const int tid  = threadIdx.x;
  const int wv   = tid >> 6;
  const int lane = tid & 63;
  const int wm = (wv >> 1) << 6;
  const int wn = (wv & 1) << 6;
  const int sr = (wv << 5) + (lane >> 3);
  const int sc = (lane & 7) << 3;
  const int fr = lane & 15;
  const int fk = (lane >> 4) << 3;

  for (int k0 = 0; k0 < K; k0 += 64) {
#pragma unroll
    for (int t = 0; t < 4; ++t) {
      int r = sr + (t << 3);
      gload_lds16(&A[(size_t)(m0 + r) * K + k0 + sc], &ldsA[r * 64 + sc]);
      gload_lds16(&B[(size_t)(n0 + r) * K + k0 + sc], &ldsB[r * 64 + sc]);
    }
    __syncthreads();
#pragma unroll
    for (int ks = 0; ks < 2; ++ks) {
      sh8 af[4], bf[4];
#pragma unroll
      for (int mt = 0; mt < 4; ++mt)
        af[mt] = *(const sh8*)&ldsA[(wm + mt * 16 + fr) * 64 + ks * 32 + fk];
#pragma unroll
      for (int nt = 0; nt < 4; ++nt)
        bf[nt] = *(const sh8*)&ldsB[(wn + nt * 16 + fr) * 64 + ks * 32 + fk];
#pragma unroll
      for (int mt = 0; mt < 4; ++mt)
#pragma unroll
        for (int nt = 0; nt < 4; ++nt)
          acc[mt][nt] = __builtin_amdgcn_mfma_f32_16x16x32_bf16(af[mt], bf[nt], acc[mt][nt], 0, 0, 0);
    }
    __syncthreads();
  }
}

// ---------------- QKV projection + scatter ----------------
__global__ __launch_bounds__(256) void k_qkv_gemm(
    const unsigned short* __restrict__ xb, const unsigned short* __restrict__ wq,
    unsigned short* __restrict__ Q, unsigned short* __restrict__ Kc,
    unsigned short* __restrict__ Vt) {
  __shared__ __align__(16) unsigned short lds[2 * 128 * 64];
  f32x4 acc[4][4];
  const f32x4 fz = {0.f, 0.f, 0.f, 0.f};
#pragma unroll
  for (int i = 0; i < 4; ++i)
#pragma unroll
    for (int j = 0; j < 4; ++j) acc[i][j] = fz;

  const int m0 = blockIdx.x * 128, n0 = blockIdx.y * 128;
  gemm_bt_core(xb, wq, 1024, m0, n0, lds, lds + 128 * 64, acc);

  const int tid = threadIdx.x, wv = tid >> 6, lane = tid & 63;
  const int wm = (wv >> 1) << 6, wn = (wv & 1) << 6;
  const int r4 = (lane >> 4) << 2, fr = lane & 15;
#pragma unroll
  for (int mt = 0; mt < 4; ++mt)
#pragma unroll
    for (int nt = 0; nt < 4; ++nt)
#pragma unroll
      for (int i = 0; i < 4; ++i) {
        int row = m0 + wm + mt * 16 + r4 + i;   // m in [0,4096)
        int col = n0 + wn + nt * 16 + fr;       // n in [0,3072)
        float v = acc[mt][nt][i];
        int b = row >> 11, lq = row & 2047;
        int which = col >> 10, rem = col & 1023;
        int h = rem >> 6, hd = rem & 63;
        size_t bh = (size_t)(b * 16 + h);
        if (which == 0)      Q [(bh * 2048 + lq) * 64 + hd] = f2b(v * 0.125f);
        else if (which == 1) Kc[(bh * 2048 + lq) * 64 + hd] = f2b(v);
        else                 Vt[(bh * 64 + hd) * 2048 + lq] = f2b(v);
      }
}

// ---------------- causal flash attention ----------------
// grid: 4096 one-wave blocks (64 thr). blockIdx = sIdx*32 + bh; strip = 127 - sIdx
// (longest first for backfill). Wave handles 16 q-rows (q = strip*16 + fr).
// Swapped QK: s = mfma(K, Q) -> S^T: lane g,fr holds kv = kvb + 16t + 4g + i, q = fr.
// Softmax per-lane (within-lane 8-reduce + xor16 + xor32). P packs straight into the
// 16x16x16 PV B-frag (k = 4g + j == our register layout): NO cross-lane transpose.
// PV: o[hb] += mfma16(V^T frag, P frag). K for tile j+1 prefetched during softmax.
__global__ __launch_bounds__(64, 4) void k_attn(
    const unsigned short* __restrict__ Q, const unsigned short* __restrict__ Kc,
    const unsigned short* __restrict__ Vt, unsigned short* __restrict__ attn) {
  const int bh   = blockIdx.x & 31;
  const int strip = 127 - (blockIdx.x >> 5);   // 0..127, longest dispatched first
  const int lane = threadIdx.x & 63;
  const int qw = strip << 4;
  const int b = bh >> 4, h = bh & 15;
  const unsigned short* Qb = Q  + (size_t)bh * 2048 * 64;
  const unsigned short* Kb = Kc + (size_t)bh * 2048 * 64;
  const unsigned short* Vb = Vt + (size_t)bh * 64 * 2048;
  const int fr = lane & 15, g = lane >> 4;
  const int fk = g << 3, r4 = g << 2;
  const f32x4 fz = {0.f, 0.f, 0.f, 0.f};

  sh8 qf[2];
#pragma unroll
  for (int ks = 0; ks < 2; ++ks)
    qf[ks] = *(const sh8*)&Qb[(size_t)(qw + fr) * 64 + ks * 32 + fk];

  f32x4 o[4];
#pragma unroll
  for (int i = 0; i < 4; ++i) o[i] = fz;
  float m_i = -1e30f, l_i = 0.f;

  const int nj = (qw + 47) >> 5;          // 32-kv tiles up to the diagonal

  // preload K frags for tile 0
  sh8 kf[2][2];
#pragma unroll
  for (int t = 0; t < 2; ++t)
#pragma unroll
    for (int ks = 0; ks < 2; ++ks)
      kf[t][ks] = *(const sh8*)&Kb[(size_t)(t * 16 + fr) * 64 + ks * 32 + fk];

  for (int j = 0; j < nj; ++j) {
    const int kvb = j << 5;
    // V frags for current tile (A-operand of 16x16x16): row d = fr, k = 4g + jj
    sh4 vf[4][2];
#pragma unroll
    for (int hb = 0; hb < 4; ++hb)
#pragma unroll
      for (int t = 0; t < 2; ++t)
        vf[hb][t] = *(const sh4*)&Vb[(size_t)(hb * 16 + fr) * 2048 + kvb + t * 16 + r4];

    // QK^T swapped: s[t] holds S^T rows kv = kvb+16t+4g+i, col q = fr
    f32x4 s[2]; s[0] = fz; s[1] = fz;
#pragma unroll
    for (int t = 0; t < 2; ++t)
#pragma unroll
      for (int ks = 0; ks < 2; ++ks)
        s[t] = __builtin_amdgcn_mfma_f32_16x16x32_bf16(kf[t][ks], qf[ks], s[t], 0, 0, 0);

    // prefetch K frags for next tile while softmax runs
    const int jn = (j + 1 < nj) ? j + 1 : j;
#pragma unroll
    for (int t = 0; t < 2; ++t)
#pragma unroll
      for (int ks = 0; ks < 2; ++ks)
        kf[t][ks] = *(const sh8*)&Kb[(size_t)((jn << 5) + t * 16 + fr) * 64 + ks * 32 + fk];

    if (j == nj - 1) {  // diagonal tile: causal mask (kv > q)
#pragma unroll
      for (int t = 0; t < 2; ++t)
#pragma unroll
        for (int i = 0; i < 4; ++i)
          if (kvb + t * 16 + r4 + i > qw + fr) s[t][i] = -1e30f;
    }
    // per-lane softmax for q = qw+fr: within-lane 8-value reduce + xor16 + xor32
    float mx = fmaxf(fmaxf(fmaxf(s[0][0], s[0][1]), fmaxf(s[0][2], s[0][3])),
                     fmaxf(fmaxf(s[1][0], s[1][1]), fmaxf(s[1][2], s[1][3])));
    mx = fmaxf(mx, __shfl_xor(mx, 16, 64));
    mx = fmaxf(mx, __shfl_xor(mx, 32, 64));
    const float mn = fmaxf(m_i, mx);
    const float scale = __expf(m_i - mn);
    m_i = mn;
    float p0[4], p1[4];
#pragma unroll
    for (int i = 0; i < 4; ++i) {
      p0[i] = __expf(s[0][i] - mn);
      p1[i] = __expf(s[1][i] - mn);
    }
    float rs = (p0[0] + p0[1]) + (p0[2] + p0[3]) + (p1[0] + p1[1]) + (p1[2] + p1[3]);
    rs += __shfl_xor(rs, 16, 64);
    rs += __shfl_xor(rs, 32, 64);
    l_i = l_i * scale + rs;
#pragma unroll
    for (int hb = 0; hb < 4; ++hb)
#pragma unroll
      for (int i = 0; i < 4; ++i) o[hb][i] *= scale;

    // P is already in 16x16x16 B-frag layout: col q = fr, k = kv_local = 4g + jj
    union { unsigned int w[2]; sh4 v; } pb0, pb1;
    pb0.w[0] = pack2(p0[0], p0[1]); pb0.w[1] = pack2(p0[2], p0[3]);  // tile t=0
    pb1.w[0] = pack2(p1[0], p1[1]); pb1.w[1] = pack2(p1[2], p1[3]);  // tile t=1

#pragma unroll
    for (int hb = 0; hb < 4; ++hb) {
      o[hb] = mfma16x16x16(vf[hb][0], pb0.v, o[hb]);
      o[hb] = mfma16x16x16(vf[hb][1], pb1.v, o[hb]);
    }
  }

  const float inv = 1.0f / l_i;
  // o layout: col = q = fr (lane), row = d = hb*16 + r4 + i -> pack i-pairs, b32 stores
  const size_t base = ((size_t)(b * 2048 + qw + fr)) * 1024 + h * 64;
#pragma unroll
  for (int hb = 0; hb < 4; ++hb)
#pragma unroll
    for (int i2 = 0; i2 < 2; ++i2) {
      unsigned int pw = pack2(o[hb][2 * i2] * inv, o[hb][2 * i2 + 1] * inv);
      *(unsigned int*)&attn[base + hb * 16 + r4 + 2 * i2] = pw;
    }
}

// ---------------- output projection + bias (fp32 out) ----------------
__global__ __launch_bounds__(256) void k_out_gemm(
    const unsigned short* __restrict__ attn, const unsigned short* __restrict__ wo,
    const float* __restrict__ bias, float* __restrict__ out) {
  __shared__ __align__(16) unsigned short lds[2 * 128 * 64];
  f32x4 acc[4][4];
  const f32x4 fz = {0.f, 0.f, 0.f, 0.f};
#pragma unroll
  for (int i = 0; i < 4; ++i)
#pragma unroll
    for (int j = 0; j < 4; ++j) acc[i][j] = fz;

  const int m0 = blockIdx.x * 128, n0 = blockIdx.y * 128;
  gemm_bt_core(attn, wo, 1024, m0, n0, lds, lds + 128 * 64, acc);

  const int tid = threadIdx.x, wv = tid >> 6, lane = tid & 63;
  const int wm = (wv >> 1) << 6, wn = (wv & 1) << 6;
  const int r4 = (lane >> 4) << 2, fr = lane & 15;
#pragma unroll
  for (int mt = 0; mt < 4; ++mt)
#pragma unroll
    for (int nt = 0; nt < 4; ++nt)
#pragma unroll
      for (int i = 0; i < 4; ++i) {
        int row = m0 + wm + mt * 16 + r4 + i;
        int col = n0 + wn + nt * 16 + fr;
        out[(size_t)row * 1024 + col] = acc[mt][nt][i] + bias[col];
      }
}

// ---------------- launch ----------------
extern "C" void kernel_launch(void* const* d_in, const int* in_sizes, int n_in,
                              void* d_out, int out_size, void* d_ws, size_t ws_size,
                              hipStream_t stream) {
  const float* x     = (const float*)d_in[0];
  const float* qkv_w = (const float*)d_in[1];
  const float* out_w = (const float*)d_in[2];
  const float* out_b = (const float*)d_in[3];
  float* out = (float*)d_out;

  unsigned short* ws   = (unsigned short*)d_ws;
  unsigned short* xb   = ws;                        // 4096*1024
  unsigned short* wq   = xb  + 4096 * 1024;         // 3072*1024
  unsigned short* wo   = wq  + 3072 * 1024;         // 1024*1024
  unsigned short* Qs   = wo  + 1024 * 1024;         // 32*2048*64
  unsigned short* Ks   = Qs  + 32 * 2048 * 64;      // 32*2048*64
  unsigned short* Vts  = Ks  + 32 * 2048 * 64;      // 32*64*2048
  unsigned short* attn = Vts + 32 * 64 * 2048;      // 4096*1024

  k_cvt<<<4096, 256, 0, stream>>>(x,     xb, 4096 * 1024);
  k_cvt<<<3072, 256, 0, stream>>>(qkv_w, wq, 3072 * 1024);
  k_cvt<<<1024, 256, 0, stream>>>(out_w, wo, 1024 * 1024);
  k_qkv_gemm<<<dim3(32, 24), 256, 0, stream>>>(xb, wq, Qs, Ks, Vts);
  k_attn<<<4096, 64, 0, stream>>>(Qs, Ks, Vts, attn);
  k_out_gemm<<<dim3(32, 8), 256, 0, stream>>>(attn, wo, out_b, out);
}